// Round 1
// baseline (98.798 us; speedup 1.0000x reference)
//
#include <hip/hip_runtime.h>

#define BB 131072
#define DD 512
#define NN 101
#define D4 (DD / 4)        // 128 float4 per row
#define TOT (BB * D4)      // 16777216 float4 total

// ---------------- center (MSE) term: sum over B,D of (e - c[label])^2 ----------------
__global__ __launch_bounds__(256) void center_sum_kernel(
    const float4* __restrict__ emb, const float4* __restrict__ ctr,
    const int* __restrict__ labels, double* __restrict__ acc)
{
    int tid    = blockIdx.x * blockDim.x + threadIdx.x;
    int stride = gridDim.x * blockDim.x;
    float local = 0.f;
    for (int i = tid; i < TOT; i += stride) {
        int s  = i >> 7;          // sample index (i / 128)
        int d4 = i & (D4 - 1);    // float4 index within row
        int lab = labels[s];      // same for 128 consecutive threads -> L1 broadcast
        float4 e = emb[i];
        float4 c = ctr[lab * D4 + d4];
        float dx = e.x - c.x;
        float dy = e.y - c.y;
        float dz = e.z - c.z;
        float dw = e.w - c.w;
        local += dx * dx + dy * dy + dz * dz + dw * dw;
    }
    // wave(64) reduce
    for (int off = 32; off > 0; off >>= 1)
        local += __shfl_down(local, off);
    __shared__ float wsum[4];
    int lane = threadIdx.x & 63;
    int wid  = threadIdx.x >> 6;
    if (lane == 0) wsum[wid] = local;
    __syncthreads();
    if (threadIdx.x == 0) {
        float b = wsum[0] + wsum[1] + wsum[2] + wsum[3];
        atomicAdd(acc, (double)b);   // fp64 atomic: avoids fp32 random-walk error (~700 abs)
    }
}

// ---------------- Gram matrix G[i][j] = W_i . W_j  (one wave per pair) ----------------
__global__ __launch_bounds__(256) void gram_kernel(
    const float4* __restrict__ W, float* __restrict__ G)
{
    int gwave = (int)((blockIdx.x * blockDim.x + threadIdx.x) >> 6);
    int lane  = threadIdx.x & 63;
    if (gwave >= NN * NN) return;
    int i = gwave / NN;
    int j = gwave % NN;
    const float4* wi = W + i * D4;
    const float4* wj = W + j * D4;
    float dot = 0.f;
#pragma unroll
    for (int r = 0; r < 2; r++) {     // lane covers d4 = lane and lane+64 (D4=128)
        int d4 = lane + r * 64;
        float4 a = wi[d4];
        float4 b = wj[d4];
        dot += a.x * b.x + a.y * b.y + a.z * b.z + a.w * b.w;
    }
    for (int off = 32; off > 0; off >>= 1)
        dot += __shfl_down(dot, off);
    if (lane == 0) G[gwave] = dot;
}

// ---------------- margin term from G + final combine ----------------
// dist[i][j] = 1 - G[i][j]/(max(sqrt(G_ii),.1)*max(sqrt(G_jj),.1))
// diagonal and |i-j|==1 get +1e9 before the row-min; since unmasked entries are
// <= 2 and masked ~1e9, skipping j in {t-1,t,t+1} is exactly equivalent.
__global__ __launch_bounds__(128) void finalize_kernel(
    const float* __restrict__ G, const double* __restrict__ acc,
    float* __restrict__ out)
{
    __shared__ float denom[NN];
    __shared__ float mind[NN];
    int t = threadIdx.x;
    if (t < NN)
        denom[t] = fmaxf(sqrtf(G[t * NN + t]), 0.1f);
    __syncthreads();
    if (t < NN) {
        float di = denom[t];
        float mn = 1e30f;
        for (int j = 0; j < NN; j++) {
            if (j >= t - 1 && j <= t + 1) continue;   // diag + adjacent masked
            float d = 1.0f - G[t * NN + j] / (di * denom[j]);
            mn = fminf(mn, d);
        }
        mind[t] = mn;
    }
    __syncthreads();
    float contrib = 0.f;
    if (t >= 1 && t < NN) {   // d_lower[i]=dist[i][i-1], paired with min_dist[1:]
        float dl = 1.0f - G[t * NN + (t - 1)] / (denom[t] * denom[t - 1]);
        contrib += fmaxf(2.0f * dl - mind[t], 0.0f);
    }
    if (t < NN - 1) {         // d_upper[i]=dist[i][i+1], paired with min_dist[:-1]
        float du = 1.0f - G[t * NN + (t + 1)] / (denom[t] * denom[t + 1]);
        contrib += fmaxf(2.0f * du - mind[t], 0.0f);
    }
    for (int off = 32; off > 0; off >>= 1)
        contrib += __shfl_down(contrib, off);
    __shared__ float wsum2[2];
    if ((t & 63) == 0) wsum2[t >> 6] = contrib;
    __syncthreads();
    if (t == 0) {
        float margin = (wsum2[0] + wsum2[1]) / (float)NN;
        out[0] = margin + (float)(acc[0] / (double)BB);
    }
}

extern "C" void kernel_launch(void* const* d_in, const int* in_sizes, int n_in,
                              void* d_out, int out_size, void* d_ws, size_t ws_size,
                              hipStream_t stream) {
    const float* emb   = (const float*)d_in[0];
    const float* ctr   = (const float*)d_in[1];
    const int*   labels = (const int*)d_in[2];
    float* out = (float*)d_out;

    double* acc = (double*)d_ws;                      // 8B fp64 accumulator
    float*  G   = (float*)((char*)d_ws + 16);         // 101*101 floats

    // zero the accumulator each call (ws is poisoned once, never re-poisoned)
    hipMemsetAsync(d_ws, 0, 16, stream);

    gram_kernel<<<(NN * NN * 64 + 255) / 256, 256, 0, stream>>>((const float4*)ctr, G);
    center_sum_kernel<<<2048, 256, 0, stream>>>((const float4*)emb, (const float4*)ctr,
                                                labels, acc);
    finalize_kernel<<<1, 128, 0, stream>>>(G, acc, out);
}

// Round 2
// 82.020 us; speedup vs baseline: 1.2046x; 1.2046x over previous
//
#include <hip/hip_runtime.h>

#define BB 131072
#define DD 512
#define NN 101
#define D4 (DD / 4)          // 128 float4 per row
#define TOT (BB * D4)        // 16777216 float4 total
#define CBLK 2048            // center-sum blocks
#define GBLK 256             // gram blocks
#define NPAIR (NN * NN)      // 10201 center pairs

// ---------------- fused: center partial sums (blocks 0..CBLK-1) + Gram (rest) ----
__global__ __launch_bounds__(256) void fused_kernel(
    const float4* __restrict__ emb, const float4* __restrict__ ctr,
    const int* __restrict__ labels,
    float* __restrict__ partial,   // [CBLK] per-block center sums
    float* __restrict__ G)         // [NN*NN] gram matrix
{
    int b = blockIdx.x;
    if (b < CBLK) {
        // ---- center (MSE) term: block-strided over all B*D4 float4 ----
        int tid    = b * 256 + threadIdx.x;
        int stride = CBLK * 256;
        float local = 0.f;
        for (int i = tid; i < TOT; i += stride) {
            int s   = i >> 7;          // sample index
            int d4  = i & (D4 - 1);    // float4 index within row
            int lab = labels[s];       // wave-uniform -> single L2 request
            float4 e = emb[i];
            float4 c = ctr[lab * D4 + d4];   // L2-resident gather (207 KB total)
            float dx = e.x - c.x;
            float dy = e.y - c.y;
            float dz = e.z - c.z;
            float dw = e.w - c.w;
            local += dx * dx + dy * dy + dz * dz + dw * dw;
        }
        for (int off = 32; off > 0; off >>= 1)
            local += __shfl_down(local, off);
        __shared__ float wsum[4];
        int lane = threadIdx.x & 63;
        int wid  = threadIdx.x >> 6;
        if (lane == 0) wsum[wid] = local;
        __syncthreads();
        if (threadIdx.x == 0)
            partial[b] = wsum[0] + wsum[1] + wsum[2] + wsum[3];  // no atomics
    } else {
        // ---- Gram: one wave per (i,j) pair, grid-stride over pairs ----
        int wv   = (b - CBLK) * 4 + (threadIdx.x >> 6);
        int lane = threadIdx.x & 63;
        for (int p = wv; p < NPAIR; p += GBLK * 4) {
            int i = p / NN;
            int j = p % NN;
            const float4* wi = ctr + i * D4;
            const float4* wj = ctr + j * D4;
            float dot = 0.f;
#pragma unroll
            for (int r = 0; r < 2; r++) {       // D4=128 = 64 lanes x 2
                int d4 = lane + r * 64;
                float4 a = wi[d4];
                float4 c = wj[d4];
                dot += a.x * c.x + a.y * c.y + a.z * c.z + a.w * c.w;
            }
            for (int off = 32; off > 0; off >>= 1)
                dot += __shfl_down(dot, off);
            if (lane == 0) G[p] = dot;
        }
    }
}

// ---------------- finalize: margin from G + center mean from partials ----------
// dist[i][j] = 1 - G[i][j]/(max(sqrt(G_ii),.1)*max(sqrt(G_jj),.1))
// diagonal and |i-j|==1 are +1e9-masked before the row min; unmasked entries
// are <= 2, so skipping j in {t-1,t,t+1} is exactly equivalent.
__global__ __launch_bounds__(256) void finalize_kernel(
    const float* __restrict__ G, const float* __restrict__ partial,
    float* __restrict__ out)
{
    int t = threadIdx.x;

    // ---- sum 2048 float partials in double (exact enough; no atomics) ----
    double dsum = 0.0;
    for (int i = t; i < CBLK; i += 256)
        dsum += (double)partial[i];
    for (int off = 32; off > 0; off >>= 1)
        dsum += __shfl_down(dsum, off);
    __shared__ double dacc[4];
    if ((t & 63) == 0) dacc[t >> 6] = dsum;

    // ---- margin term ----
    __shared__ float denom[NN];
    __shared__ float mind[NN];
    if (t < NN)
        denom[t] = fmaxf(sqrtf(G[t * NN + t]), 0.1f);
    __syncthreads();
    if (t < NN) {
        float di = denom[t];
        float mn = 1e30f;
        for (int j = 0; j < NN; j++) {
            if (j >= t - 1 && j <= t + 1) continue;   // diag + adjacent masked
            float d = 1.0f - G[t * NN + j] / (di * denom[j]);
            mn = fminf(mn, d);
        }
        mind[t] = mn;
    }
    __syncthreads();
    float contrib = 0.f;
    if (t >= 1 && t < NN) {        // d_lower[i]=dist[i][i-1] vs min_dist[1:]
        float dl = 1.0f - G[t * NN + (t - 1)] / (denom[t] * denom[t - 1]);
        contrib += fmaxf(2.0f * dl - mind[t], 0.0f);
    }
    if (t < NN - 1) {              // d_upper[i]=dist[i][i+1] vs min_dist[:-1]
        float du = 1.0f - G[t * NN + (t + 1)] / (denom[t] * denom[t + 1]);
        contrib += fmaxf(2.0f * du - mind[t], 0.0f);
    }
    for (int off = 32; off > 0; off >>= 1)
        contrib += __shfl_down(contrib, off);
    __shared__ float wsum2[4];
    if ((t & 63) == 0) wsum2[t >> 6] = contrib;
    __syncthreads();
    if (t == 0) {
        float margin = (wsum2[0] + wsum2[1] + wsum2[2] + wsum2[3]) / (float)NN;
        double center = (dacc[0] + dacc[1] + dacc[2] + dacc[3]) / (double)BB;
        out[0] = margin + (float)center;
    }
}

extern "C" void kernel_launch(void* const* d_in, const int* in_sizes, int n_in,
                              void* d_out, int out_size, void* d_ws, size_t ws_size,
                              hipStream_t stream) {
    const float* emb    = (const float*)d_in[0];
    const float* ctr    = (const float*)d_in[1];
    const int*   labels = (const int*)d_in[2];
    float* out = (float*)d_out;

    float* partial = (float*)d_ws;                          // CBLK floats
    float* G       = (float*)((char*)d_ws + CBLK * 4);      // NN*NN floats
    // Every ws element used is unconditionally rewritten each call -> no memset.

    fused_kernel<<<CBLK + GBLK, 256, 0, stream>>>(
        (const float4*)emb, (const float4*)ctr, labels, partial, G);
    finalize_kernel<<<1, 256, 0, stream>>>(G, partial, out);
}